// Round 13
// baseline (345.576 us; speedup 1.0000x reference)
//
#include <hip/hip_runtime.h>
#include <hip/hip_bf16.h>
#include <hip/hip_fp16.h>

// Problem constants (fixed by the reference)
#define NN 100000
#define NE 6400000
#define F_IN 50
#define H1 30
#define H2 25

// Bucketing constants
#define BSZ 128                    // dst nodes per bucket (dstoff = 7 bits)
#define NB 782                     // ceil(NN / BSZ)
#define NBLK 256                   // blocks for hist/place
#define CHUNK 25000                // NE / NBLK (exact)
#define EPT ((CHUNK + 1023) / 1024)    // 25 edges per thread in k_place
#define EPTB 12                    // keys per thread in k_bsort (1024 thr)
#define CAP (EPTB * 1024)          // 12,288 (mean run 8184, sigma 90 -> 45-sigma guard)
#define M_TOT (NB * NBLK)          // 200,192 scan elements
#define SBLK ((M_TOT + 1023) / 1024)   // 196

// ---------------------------------------------------------------------------
// 1) per-(block,bucket) histogram of dst buckets (LDS atomics only)
__global__ __launch_bounds__(1024) void k_hist(const int* __restrict__ dst,
                                               int* __restrict__ cntT) {
    __shared__ int h[NB];
    for (int i = threadIdx.x; i < NB; i += 1024) h[i] = 0;
    __syncthreads();
    int base = blockIdx.x * CHUNK;
    for (int i = threadIdx.x; i < CHUNK; i += 1024)
        atomicAdd(&h[dst[base + i] >> 7], 1);
    __syncthreads();
    for (int i = threadIdx.x; i < NB; i += 1024)
        cntT[i * NBLK + blockIdx.x] = h[i];
}

// 2a) per-1024-slice exclusive scan (LDS) + slice totals
__global__ __launch_bounds__(1024) void k_scan1(int* __restrict__ buf,
                                                int* __restrict__ bsum) {
    __shared__ int tmp[1024];
    int b = blockIdx.x, t = threadIdx.x;
    int i = b * 1024 + t;
    int v = (i < M_TOT) ? buf[i] : 0;
    tmp[t] = v;
    __syncthreads();
    for (int off = 1; off < 1024; off <<= 1) {
        int u = (t >= off) ? tmp[t - off] : 0;
        __syncthreads();
        tmp[t] += u;
        __syncthreads();
    }
    if (i < M_TOT) buf[i] = tmp[t] - v;        // exclusive
    if (t == 1023) bsum[b] = tmp[1023];
}

// 2b) exclusive scan of the SBLK slice totals
__global__ __launch_bounds__(256) void k_scan2(int* __restrict__ bsum) {
    __shared__ int tmp[256];
    int t = threadIdx.x;
    int v = (t < SBLK) ? bsum[t] : 0;
    tmp[t] = v;
    __syncthreads();
    for (int off = 1; off < 256; off <<= 1) {
        int u = (t >= off) ? tmp[t - off] : 0;
        __syncthreads();
        tmp[t] += u;
        __syncthreads();
    }
    if (t < SBLK) bsum[t] = tmp[t] - v;        // exclusive
}

// 2c) propagate slice offsets
__global__ __launch_bounds__(1024) void k_scan3(int* __restrict__ buf,
                                                const int* __restrict__ bsum) {
    int i = blockIdx.x * 1024 + threadIdx.x;
    if (i < M_TOT) buf[i] += bsum[blockIdx.x];
}

// 3) place edges: in-LDS counting sort of the block's chunk, then per-bucket
//    COALESCED write-out (contiguous runs -> full L2 lines, no 4B scatter)
__global__ __launch_bounds__(1024) void k_place(const int* __restrict__ src,
                                                const int* __restrict__ dst,
                                                const int* __restrict__ offT,
                                                int* __restrict__ ebuf) {
    __shared__ int keys[CHUNK];      // 100,000 B
    __shared__ int cnt[NB];          // hist -> cursor -> end
    __shared__ int lstart[NB];       // local run starts
    __shared__ int gbase[NB];        // global run starts for this block
    __shared__ int scanT[1024];
    int t = threadIdx.x;
    int base = blockIdx.x * CHUNK;
    for (int i = t; i < NB; i += 1024) {
        cnt[i] = 0;
        gbase[i] = offT[i * NBLK + blockIdx.x];
    }
    __syncthreads();
    // phase 1: load edges into registers (static indexing), LDS histogram
    int sreg[EPT], breg[EPT];
#pragma unroll
    for (int k = 0; k < EPT; ++k) {
        int idx = k * 1024 + t;
        if (idx < CHUNK) {
            int d = dst[base + idx];
            int s = src[base + idx];
            breg[k] = d >> 7;
            sreg[k] = (s << 7) | (d & 127);
            atomicAdd(&cnt[breg[k]], 1);
        }
    }
    __syncthreads();
    // phase 2: exclusive scan of cnt (NB=782 <= 1024)
    int v = (t < NB) ? cnt[t] : 0;
    scanT[t] = v;
    __syncthreads();
    for (int off = 1; off < 1024; off <<= 1) {
        int u = (t >= off) ? scanT[t - off] : 0;
        __syncthreads();
        scanT[t] += u;
        __syncthreads();
    }
    if (t < NB) { int e = scanT[t] - v; lstart[t] = e; cnt[t] = e; }
    __syncthreads();
    // phase 3: scatter keys into LDS, bucket-grouped
#pragma unroll
    for (int k = 0; k < EPT; ++k) {
        int idx = k * 1024 + t;
        if (idx < CHUNK) {
            int p = atomicAdd(&cnt[breg[k]], 1);
            keys[p] = sreg[k];
        }
    }
    __syncthreads();
    // phase 4: per-bucket coalesced write-out (cnt[b] is now run end)
    int wv = t >> 6, ln = t & 63;
    for (int b = wv; b < NB; b += 16) {
        int s0 = lstart[b], e0 = cnt[b], gb = gbase[b];
        for (int off = ln; off < e0 - s0; off += 64)
            ebuf[gb + off] = keys[s0 + off];
    }
}

// 4) within-bucket counting sort: keys staged in REGISTERS (static unroll),
//    1024 threads, ~1KB LDS -> full occupancy
__global__ __launch_bounds__(1024) void k_bsort(int* __restrict__ ebuf,
                                                const int* __restrict__ offT,
                                                int* __restrict__ rowptr) {
    __shared__ int cnt[BSZ];
    __shared__ int loc[BSZ];
    int b = blockIdx.x;
    int beg = offT[b * NBLK];
    int end = (b == NB - 1) ? NE : offT[(b + 1) * NBLK];
    int m = end - beg; if (m > CAP) m = CAP;   // 45-sigma guard, never triggers
    int t = threadIdx.x;
    if (t < BSZ) cnt[t] = 0;
    __syncthreads();
    int keys[EPTB];
#pragma unroll
    for (int k = 0; k < EPTB; ++k) {
        int idx = k * 1024 + t;
        if (idx < m) {
            int key = ebuf[beg + idx];     // coalesced
            keys[k] = key;
            atomicAdd(&cnt[key & 127], 1);
        }
    }
    __syncthreads();
    // inclusive scan of cnt (first 128 threads)
    if (t < BSZ) loc[t] = cnt[t];
    __syncthreads();
    for (int off = 1; off < BSZ; off <<= 1) {
        int v = (t < BSZ && t >= off) ? loc[t - off] : 0;
        __syncthreads();
        if (t < BSZ) loc[t] += v;
        __syncthreads();
    }
    int nbase = b * BSZ;
    int nloc = NN - nbase; if (nloc > BSZ) nloc = BSZ;
    if (t < nloc) {
        int excl = loc[t] - cnt[t];
        rowptr[nbase + t] = beg + excl;
        if (t == nloc - 1) rowptr[nbase + nloc] = beg + loc[t];
    }
    __syncthreads();
    if (t < BSZ) cnt[t] = beg + loc[t] - cnt[t];   // cursors
    __syncthreads();
#pragma unroll
    for (int k = 0; k < EPTB; ++k) {
        int idx = k * 1024 + t;
        if (idx < m) {
            int key = keys[k];
            int p = atomicAdd(&cnt[key & 127], 1);
            ebuf[p] = key >> 7;            // scattered within 33KB run -> L2 merges
        }
    }
}

// 5) h1 halves = fp16( dinv * (x @ W1) ): two [NN][16] tables.
//    16-lane-group-per-node micro-GEMM: low VGPR, small LDS, full occupancy.
__global__ __launch_bounds__(256) void k_gemm1(const float* __restrict__ x,
                                               const float* __restrict__ W1,
                                               const int* __restrict__ rowptr,
                                               __half* __restrict__ h1lo,
                                               __half* __restrict__ h1hi) {
    __shared__ float Wp[F_IN * 32];      // 6400 B, padded rows of 32
    __shared__ float xs[16 * F_IN];      // 3200 B, 16 node rows
    __shared__ float dns[16];
    int t = threadIdx.x;
    for (int i = t; i < F_IN * 32; i += 256) {
        int k = i >> 5, j = i & 31;
        Wp[i] = (j < H1) ? W1[k * H1 + j] : 0.f;
    }
    int nbase = blockIdx.x * 16;         // NN = 6250*16 exactly
    for (int i = t; i < 16 * F_IN; i += 256)
        xs[i] = x[nbase * F_IN + i];     // coalesced
    if (t < 16) {
        int n = nbase + t;
        dns[t] = rsqrtf((float)(rowptr[n + 1] - rowptr[n] + 1));
    }
    __syncthreads();
    int g = t >> 4;                      // node group 0..15
    int l = t & 15;                      // lane: features 2l, 2l+1
    float a0 = 0.f, a1 = 0.f;
#pragma unroll
    for (int k = 0; k < F_IN; ++k) {
        float xk = xs[g * F_IN + k];                      // broadcast
        float2 w = *(const float2*)&Wp[k * 32 + 2 * l];   // conflict-free
        a0 = fmaf(xk, w.x, a0);
        a1 = fmaf(xk, w.y, a1);
    }
    float dn = dns[g];
    __half2 hh = __halves2half2(__float2half(dn * a0), __float2half(dn * a1));
    int n = nbase + g;
    if (l < 8) *(__half2*)&h1lo[n * 16 + 2 * l] = hh;
    else       *(__half2*)&h1hi[n * 16 + 2 * (l - 8)] = hh;
}

// 6) layer-1 aggregate over ONE feature half (table L2-resident): 8-lane
//    groups, half2/lane, 16-deep gather batches (128 lines in flight/wave).
//    Epilogue: bias+ReLU (per-feature) -> a_buf fp16 [NN][32]
__global__ __launch_bounds__(256) void k_aggh1(const int* __restrict__ ebuf,
                                               const int* __restrict__ rowptr,
                                               const __half* __restrict__ tab,
                                               const float* __restrict__ b1,
                                               int fbase,
                                               __half* __restrict__ a_buf) {
    __shared__ float bb[16];
    if (threadIdx.x < 16) {
        int j = fbase + threadIdx.x;
        bb[threadIdx.x] = (j < H1) ? b1[j] : 0.f;
    }
    __syncthreads();
    int g = threadIdx.x >> 3;        // 0..31 node-group
    int l = threadIdx.x & 7;         // lane; features fbase+2l, fbase+2l+1
    int n = blockIdx.x * 32 + g;     // NN = 3125*32 exactly
    int beg = rowptr[n], end = rowptr[n + 1];
    int m = end - beg;
    float ax = 0.f, ay = 0.f;
    int p = beg;
    int lim16 = beg + (m & ~15);
    for (; p < lim16; p += 16) {
        int sv0 = __builtin_nontemporal_load(&ebuf[p + l]);
        int sv1 = __builtin_nontemporal_load(&ebuf[p + 8 + l]);
        int ss[16]; __half2 vv[16];
#pragma unroll
        for (int u = 0; u < 8; ++u) ss[u] = __shfl(sv0, u, 8);
#pragma unroll
        for (int u = 0; u < 8; ++u) ss[8 + u] = __shfl(sv1, u, 8);
#pragma unroll
        for (int u = 0; u < 16; ++u) vv[u] = *(const __half2*)&tab[ss[u] * 16 + 2 * l];
#pragma unroll
        for (int u = 0; u < 16; ++u) { float2 f = __half22float2(vv[u]); ax += f.x; ay += f.y; }
    }
    if (m & 8) {
        int sv = __builtin_nontemporal_load(&ebuf[p + l]);
        int ss[8]; __half2 vv[8];
#pragma unroll
        for (int u = 0; u < 8; ++u) ss[u] = __shfl(sv, u, 8);
#pragma unroll
        for (int u = 0; u < 8; ++u) vv[u] = *(const __half2*)&tab[ss[u] * 16 + 2 * l];
#pragma unroll
        for (int u = 0; u < 8; ++u) { float2 f = __half22float2(vv[u]); ax += f.x; ay += f.y; }
        p += 8;
    }
    int rem = end - p;
    if (rem) {
        int sv = (l < rem) ? ebuf[p + l] : 0;
        for (int i = 0; i < rem; ++i) {   // group-uniform bound
            int s = __shfl(sv, i, 8);
            float2 f = __half22float2(*(const __half2*)&tab[s * 16 + 2 * l]);
            ax += f.x; ay += f.y;
        }
    }
    float dn = rsqrtf((float)(m + 1));
    float2 self = __half22float2(*(const __half2*)&tab[n * 16 + 2 * l]);
    int j0 = fbase + 2 * l, j1 = j0 + 1;
    float v0 = (j0 < H1) ? fmaxf(dn * (ax + self.x) + bb[2 * l], 0.f) : 0.f;
    float v1 = (j1 < H1) ? fmaxf(dn * (ay + self.y) + bb[2 * l + 1], 0.f) : 0.f;
    *(__half2*)&a_buf[n * 32 + fbase + 2 * l] =
        __halves2half2(__float2half(v0), __float2half(v1));
}

// 7) t2 halves = fp16( dinv * (a @ W2) ): same 16-lane-group micro-GEMM.
__global__ __launch_bounds__(256) void k_gemm2(const __half* __restrict__ a_buf,
                                               const float* __restrict__ W2,
                                               const int* __restrict__ rowptr,
                                               __half* __restrict__ t2lo,
                                               __half* __restrict__ t2hi) {
    __shared__ float Wp[H1 * 32];        // 3840 B, padded rows of 32
    __shared__ float as2[16 * 33];       // 2112 B, stride-33 pad
    __shared__ float dns[16];
    int t = threadIdx.x;
    for (int i = t; i < H1 * 32; i += 256) {
        int k = i >> 5, j = i & 31;
        Wp[i] = (j < H2) ? W2[k * H2 + j] : 0.f;
    }
    int nbase = blockIdx.x * 16;         // NN = 6250*16 exactly
    {
        // 16 rows x 32 halves = 256 half2: thread i loads half2 #i (coalesced)
        __half2 hv = *(const __half2*)&a_buf[nbase * 32 + 2 * t];
        float2 f = __half22float2(hv);
        int r = t >> 4;                  // row
        int c = (t & 15) * 2;            // col pair
        as2[r * 33 + c]     = f.x;
        as2[r * 33 + c + 1] = f.y;
    }
    if (t < 16) {
        int n = nbase + t;
        dns[t] = rsqrtf((float)(rowptr[n + 1] - rowptr[n] + 1));
    }
    __syncthreads();
    int g = t >> 4;
    int l = t & 15;
    float a0 = 0.f, a1 = 0.f;
#pragma unroll
    for (int k = 0; k < H1; ++k) {
        float ak = as2[g * 33 + k];                       // broadcast
        float2 w = *(const float2*)&Wp[k * 32 + 2 * l];
        a0 = fmaf(ak, w.x, a0);
        a1 = fmaf(ak, w.y, a1);
    }
    float dn = dns[g];
    __half2 hh = __halves2half2(__float2half(dn * a0), __float2half(dn * a1));
    int n = nbase + g;
    if (l < 8) *(__half2*)&t2lo[n * 16 + 2 * l] = hh;
    else       *(__half2*)&t2hi[n * 16 + 2 * (l - 8)] = hh;
}

// 8) layer-2 aggregate over ONE feature half -> out (+ self + b2)
//    Same 16-deep pipelined gather structure.
__global__ __launch_bounds__(256) void k_aggh2(const int* __restrict__ ebuf,
                                               const int* __restrict__ rowptr,
                                               const __half* __restrict__ tab,
                                               const float* __restrict__ b2,
                                               int fbase,
                                               float* __restrict__ out) {
    __shared__ float bb[16];
    if (threadIdx.x < 16) {
        int j = fbase + threadIdx.x;
        bb[threadIdx.x] = (j < H2) ? b2[j] : 0.f;
    }
    __syncthreads();
    int g = threadIdx.x >> 3;
    int l = threadIdx.x & 7;
    int n = blockIdx.x * 32 + g;
    int beg = rowptr[n], end = rowptr[n + 1];
    int m = end - beg;
    float ax = 0.f, ay = 0.f;
    int p = beg;
    int lim16 = beg + (m & ~15);
    for (; p < lim16; p += 16) {
        int sv0 = __builtin_nontemporal_load(&ebuf[p + l]);
        int sv1 = __builtin_nontemporal_load(&ebuf[p + 8 + l]);
        int ss[16]; __half2 vv[16];
#pragma unroll
        for (int u = 0; u < 8; ++u) ss[u] = __shfl(sv0, u, 8);
#pragma unroll
        for (int u = 0; u < 8; ++u) ss[8 + u] = __shfl(sv1, u, 8);
#pragma unroll
        for (int u = 0; u < 16; ++u) vv[u] = *(const __half2*)&tab[ss[u] * 16 + 2 * l];
#pragma unroll
        for (int u = 0; u < 16; ++u) { float2 f = __half22float2(vv[u]); ax += f.x; ay += f.y; }
    }
    if (m & 8) {
        int sv = __builtin_nontemporal_load(&ebuf[p + l]);
        int ss[8]; __half2 vv[8];
#pragma unroll
        for (int u = 0; u < 8; ++u) ss[u] = __shfl(sv, u, 8);
#pragma unroll
        for (int u = 0; u < 8; ++u) vv[u] = *(const __half2*)&tab[ss[u] * 16 + 2 * l];
#pragma unroll
        for (int u = 0; u < 8; ++u) { float2 f = __half22float2(vv[u]); ax += f.x; ay += f.y; }
        p += 8;
    }
    int rem = end - p;
    if (rem) {
        int sv = (l < rem) ? ebuf[p + l] : 0;
        for (int i = 0; i < rem; ++i) {
            int s = __shfl(sv, i, 8);
            float2 f = __half22float2(*(const __half2*)&tab[s * 16 + 2 * l]);
            ax += f.x; ay += f.y;
        }
    }
    float dn = rsqrtf((float)(m + 1));
    float2 self = __half22float2(*(const __half2*)&tab[n * 16 + 2 * l]);
    int j0 = fbase + 2 * l, j1 = j0 + 1;
    if (j0 < H2) out[n * H2 + j0] = dn * (ax + self.x) + bb[2 * l];
    if (j1 < H2) out[n * H2 + j1] = dn * (ay + self.y) + bb[2 * l + 1];
}

// ---------------------------------------------------------------------------
extern "C" void kernel_launch(void* const* d_in, const int* in_sizes, int n_in,
                              void* d_out, int out_size, void* d_ws, size_t ws_size,
                              hipStream_t stream) {
    const float* x   = (const float*)d_in[0];
    const int*   ei  = (const int*)d_in[1];   // [2, NE]: row 0 = src, row 1 = dst
    const float* W1  = (const float*)d_in[2];
    const float* b1  = (const float*)d_in[3];
    const float* W2  = (const float*)d_in[4];
    const float* b2  = (const float*)d_in[5];
    float*       out = (float*)d_out;

    const int* src = ei;
    const int* dst = ei + NE;

    // workspace layout (bytes, 128B-aligned) -- total 46,001,920
    char* ws = (char*)d_ws;
    int*    rowptr = (int*)   (ws + 0);           //   400,004 B (NN+1)
    int*    offT   = (int*)   (ws + 400128);      //   800,768 B (NB*NBLK)
    int*    bsum   = (int*)   (ws + 1201024);     //       784 B (SBLK)
    __half* h1lo   = (__half*)(ws + 1201920);     //  3,200,000 B (NN x 16)
    __half* h1hi   = (__half*)(ws + 4401920);     //  3,200,000 B
    __half* abuf   = (__half*)(ws + 7601920);     //  6,400,000 B (NN x 32)
    __half* t2lo   = (__half*)(ws + 14001920);    //  3,200,000 B
    __half* t2hi   = (__half*)(ws + 17201920);    //  3,200,000 B
    int*    ebuf   = (int*)   (ws + 20401920);    // 25,600,000 B

    k_hist <<<NBLK, 1024, 0, stream>>>(dst, offT);
    k_scan1<<<SBLK, 1024, 0, stream>>>(offT, bsum);
    k_scan2<<<1, 256, 0, stream>>>(bsum);
    k_scan3<<<SBLK, 1024, 0, stream>>>(offT, bsum);
    k_place<<<NBLK, 1024, 0, stream>>>(src, dst, offT, ebuf);
    k_bsort<<<NB, 1024, 0, stream>>>(ebuf, offT, rowptr);
    k_gemm1<<<NN / 16, 256, 0, stream>>>(x, W1, rowptr, h1lo, h1hi);
    k_aggh1<<<NN / 32, 256, 0, stream>>>(ebuf, rowptr, h1lo, b1, 0,  abuf);
    k_aggh1<<<NN / 32, 256, 0, stream>>>(ebuf, rowptr, h1hi, b1, 16, abuf);
    k_gemm2<<<NN / 16, 256, 0, stream>>>(abuf, W2, rowptr, t2lo, t2hi);
    k_aggh2<<<NN / 32, 256, 0, stream>>>(ebuf, rowptr, t2lo, b2, 0,  out);
    k_aggh2<<<NN / 32, 256, 0, stream>>>(ebuf, rowptr, t2hi, b2, 16, out);
}

// Round 14
// 296.060 us; speedup vs baseline: 1.1672x; 1.1672x over previous
//
#include <hip/hip_runtime.h>
#include <hip/hip_bf16.h>
#include <hip/hip_fp16.h>

// Problem constants (fixed by the reference)
#define NN 100000
#define NE 6400000
#define F_IN 50
#define H1 30
#define H2 25

// Bucketing constants
#define BSZ 128                    // dst nodes per bucket (dstoff = 7 bits)
#define NB 782                     // ceil(NN / BSZ)
#define NBLK 256                   // blocks for hist/place
#define CHUNK 25000                // NE / NBLK (exact)
#define EPT ((CHUNK + 1023) / 1024)    // 25 edges per thread in k_place
#define EPTB 12                    // keys per thread in k_bsort (1024 thr)
#define CAP (EPTB * 1024)          // 12,288 (mean run 8184, sigma 90 -> 45-sigma guard)
#define M_TOT (NB * NBLK)          // 200,192 scan elements
#define SBLK ((M_TOT + 1023) / 1024)   // 196

// ---------------------------------------------------------------------------
// 1) per-(block,bucket) histogram of dst buckets (LDS atomics only)
__global__ __launch_bounds__(1024) void k_hist(const int* __restrict__ dst,
                                               int* __restrict__ cntT) {
    __shared__ int h[NB];
    for (int i = threadIdx.x; i < NB; i += 1024) h[i] = 0;
    __syncthreads();
    int base = blockIdx.x * CHUNK;
    for (int i = threadIdx.x; i < CHUNK; i += 1024)
        atomicAdd(&h[dst[base + i] >> 7], 1);
    __syncthreads();
    for (int i = threadIdx.x; i < NB; i += 1024)
        cntT[i * NBLK + blockIdx.x] = h[i];
}

// 2a) per-1024-slice exclusive scan (LDS) + slice totals
__global__ __launch_bounds__(1024) void k_scan1(int* __restrict__ buf,
                                                int* __restrict__ bsum) {
    __shared__ int tmp[1024];
    int b = blockIdx.x, t = threadIdx.x;
    int i = b * 1024 + t;
    int v = (i < M_TOT) ? buf[i] : 0;
    tmp[t] = v;
    __syncthreads();
    for (int off = 1; off < 1024; off <<= 1) {
        int u = (t >= off) ? tmp[t - off] : 0;
        __syncthreads();
        tmp[t] += u;
        __syncthreads();
    }
    if (i < M_TOT) buf[i] = tmp[t] - v;        // exclusive
    if (t == 1023) bsum[b] = tmp[1023];
}

// 2b) exclusive scan of the SBLK slice totals
__global__ __launch_bounds__(256) void k_scan2(int* __restrict__ bsum) {
    __shared__ int tmp[256];
    int t = threadIdx.x;
    int v = (t < SBLK) ? bsum[t] : 0;
    tmp[t] = v;
    __syncthreads();
    for (int off = 1; off < 256; off <<= 1) {
        int u = (t >= off) ? tmp[t - off] : 0;
        __syncthreads();
        tmp[t] += u;
        __syncthreads();
    }
    if (t < SBLK) bsum[t] = tmp[t] - v;        // exclusive
}

// 2c) propagate slice offsets
__global__ __launch_bounds__(1024) void k_scan3(int* __restrict__ buf,
                                                const int* __restrict__ bsum) {
    int i = blockIdx.x * 1024 + threadIdx.x;
    if (i < M_TOT) buf[i] += bsum[blockIdx.x];
}

// 3) place edges: in-LDS counting sort of the block's chunk, then per-bucket
//    COALESCED write-out (contiguous runs -> full L2 lines, no 4B scatter)
__global__ __launch_bounds__(1024) void k_place(const int* __restrict__ src,
                                                const int* __restrict__ dst,
                                                const int* __restrict__ offT,
                                                int* __restrict__ ebuf) {
    __shared__ int keys[CHUNK];      // 100,000 B
    __shared__ int cnt[NB];          // hist -> cursor -> end
    __shared__ int lstart[NB];       // local run starts
    __shared__ int gbase[NB];        // global run starts for this block
    __shared__ int scanT[1024];
    int t = threadIdx.x;
    int base = blockIdx.x * CHUNK;
    for (int i = t; i < NB; i += 1024) {
        cnt[i] = 0;
        gbase[i] = offT[i * NBLK + blockIdx.x];
    }
    __syncthreads();
    // phase 1: load edges into registers (static indexing), LDS histogram
    int sreg[EPT], breg[EPT];
#pragma unroll
    for (int k = 0; k < EPT; ++k) {
        int idx = k * 1024 + t;
        if (idx < CHUNK) {
            int d = dst[base + idx];
            int s = src[base + idx];
            breg[k] = d >> 7;
            sreg[k] = (s << 7) | (d & 127);
            atomicAdd(&cnt[breg[k]], 1);
        }
    }
    __syncthreads();
    // phase 2: exclusive scan of cnt (NB=782 <= 1024)
    int v = (t < NB) ? cnt[t] : 0;
    scanT[t] = v;
    __syncthreads();
    for (int off = 1; off < 1024; off <<= 1) {
        int u = (t >= off) ? scanT[t - off] : 0;
        __syncthreads();
        scanT[t] += u;
        __syncthreads();
    }
    if (t < NB) { int e = scanT[t] - v; lstart[t] = e; cnt[t] = e; }
    __syncthreads();
    // phase 3: scatter keys into LDS, bucket-grouped
#pragma unroll
    for (int k = 0; k < EPT; ++k) {
        int idx = k * 1024 + t;
        if (idx < CHUNK) {
            int p = atomicAdd(&cnt[breg[k]], 1);
            keys[p] = sreg[k];
        }
    }
    __syncthreads();
    // phase 4: per-bucket coalesced write-out (cnt[b] is now run end)
    int wv = t >> 6, ln = t & 63;
    for (int b = wv; b < NB; b += 16) {
        int s0 = lstart[b], e0 = cnt[b], gb = gbase[b];
        for (int off = ln; off < e0 - s0; off += 64)
            ebuf[gb + off] = keys[s0 + off];
    }
}

// 4) within-bucket counting sort: keys staged in REGISTERS (static unroll),
//    1024 threads, ~1KB LDS -> full occupancy
__global__ __launch_bounds__(1024) void k_bsort(int* __restrict__ ebuf,
                                                const int* __restrict__ offT,
                                                int* __restrict__ rowptr) {
    __shared__ int cnt[BSZ];
    __shared__ int loc[BSZ];
    int b = blockIdx.x;
    int beg = offT[b * NBLK];
    int end = (b == NB - 1) ? NE : offT[(b + 1) * NBLK];
    int m = end - beg; if (m > CAP) m = CAP;   // 45-sigma guard, never triggers
    int t = threadIdx.x;
    if (t < BSZ) cnt[t] = 0;
    __syncthreads();
    int keys[EPTB];
#pragma unroll
    for (int k = 0; k < EPTB; ++k) {
        int idx = k * 1024 + t;
        if (idx < m) {
            int key = ebuf[beg + idx];     // coalesced
            keys[k] = key;
            atomicAdd(&cnt[key & 127], 1);
        }
    }
    __syncthreads();
    // inclusive scan of cnt (first 128 threads)
    if (t < BSZ) loc[t] = cnt[t];
    __syncthreads();
    for (int off = 1; off < BSZ; off <<= 1) {
        int v = (t < BSZ && t >= off) ? loc[t - off] : 0;
        __syncthreads();
        if (t < BSZ) loc[t] += v;
        __syncthreads();
    }
    int nbase = b * BSZ;
    int nloc = NN - nbase; if (nloc > BSZ) nloc = BSZ;
    if (t < nloc) {
        int excl = loc[t] - cnt[t];
        rowptr[nbase + t] = beg + excl;
        if (t == nloc - 1) rowptr[nbase + nloc] = beg + loc[t];
    }
    __syncthreads();
    if (t < BSZ) cnt[t] = beg + loc[t] - cnt[t];   // cursors
    __syncthreads();
#pragma unroll
    for (int k = 0; k < EPTB; ++k) {
        int idx = k * 1024 + t;
        if (idx < m) {
            int key = keys[k];
            int p = atomicAdd(&cnt[key & 127], 1);
            ebuf[p] = key >> 7;            // scattered within 33KB run -> L2 merges
        }
    }
}

// 5) h1 halves = fp16( dinv * (x @ W1) ): two [NN][16] tables.
//    16-lane-group-per-node micro-GEMM: low VGPR, small LDS, full occupancy.
__global__ __launch_bounds__(256) void k_gemm1(const float* __restrict__ x,
                                               const float* __restrict__ W1,
                                               const int* __restrict__ rowptr,
                                               __half* __restrict__ h1lo,
                                               __half* __restrict__ h1hi) {
    __shared__ float Wp[F_IN * 32];      // 6400 B, padded rows of 32
    __shared__ float xs[16 * F_IN];      // 3200 B, 16 node rows
    __shared__ float dns[16];
    int t = threadIdx.x;
    for (int i = t; i < F_IN * 32; i += 256) {
        int k = i >> 5, j = i & 31;
        Wp[i] = (j < H1) ? W1[k * H1 + j] : 0.f;
    }
    int nbase = blockIdx.x * 16;         // NN = 6250*16 exactly
    for (int i = t; i < 16 * F_IN; i += 256)
        xs[i] = x[nbase * F_IN + i];     // coalesced
    if (t < 16) {
        int n = nbase + t;
        dns[t] = rsqrtf((float)(rowptr[n + 1] - rowptr[n] + 1));
    }
    __syncthreads();
    int g = t >> 4;                      // node group 0..15
    int l = t & 15;                      // lane: features 2l, 2l+1
    float a0 = 0.f, a1 = 0.f;
#pragma unroll
    for (int k = 0; k < F_IN; ++k) {
        float xk = xs[g * F_IN + k];                      // broadcast
        float2 w = *(const float2*)&Wp[k * 32 + 2 * l];   // conflict-free
        a0 = fmaf(xk, w.x, a0);
        a1 = fmaf(xk, w.y, a1);
    }
    float dn = dns[g];
    __half2 hh = __halves2half2(__float2half(dn * a0), __float2half(dn * a1));
    int n = nbase + g;
    if (l < 8) *(__half2*)&h1lo[n * 16 + 2 * l] = hh;
    else       *(__half2*)&h1hi[n * 16 + 2 * (l - 8)] = hh;
}

// 6) layer-1 aggregate over ONE feature half (table L2-resident): 8-lane
//    groups, half2/lane, 8-deep batch -> 64 rows in flight per wave.
//    Epilogue: bias+ReLU (per-feature) -> a_buf fp16 [NN][32]
__global__ __launch_bounds__(256) void k_aggh1(const int* __restrict__ ebuf,
                                               const int* __restrict__ rowptr,
                                               const __half* __restrict__ tab,
                                               const float* __restrict__ b1,
                                               int fbase,
                                               __half* __restrict__ a_buf) {
    __shared__ float bb[16];
    if (threadIdx.x < 16) {
        int j = fbase + threadIdx.x;
        bb[threadIdx.x] = (j < H1) ? b1[j] : 0.f;
    }
    __syncthreads();
    int g = threadIdx.x >> 3;        // 0..31 node-group
    int l = threadIdx.x & 7;         // lane; features fbase+2l, fbase+2l+1
    int n = blockIdx.x * 32 + g;     // NN = 3125*32 exactly
    int beg = rowptr[n], end = rowptr[n + 1];
    int m = end - beg;
    int nfull = m & ~7;
    float ax = 0.f, ay = 0.f;
    for (int base = beg; base < beg + nfull; base += 8) {
        int sv = ebuf[base + l];
        int ss[8]; __half2 vv[8];
#pragma unroll
        for (int u = 0; u < 8; ++u) ss[u] = __shfl(sv, u, 8);
#pragma unroll
        for (int u = 0; u < 8; ++u) vv[u] = *(const __half2*)&tab[ss[u] * 16 + 2 * l];
#pragma unroll
        for (int u = 0; u < 8; ++u) { float2 f = __half22float2(vv[u]); ax += f.x; ay += f.y; }
    }
    int rem = m - nfull;
    if (rem) {
        int sv = (l < rem) ? ebuf[beg + nfull + l] : 0;
        for (int i = 0; i < rem; ++i) {   // group-uniform bound
            int s = __shfl(sv, i, 8);
            float2 f = __half22float2(*(const __half2*)&tab[s * 16 + 2 * l]);
            ax += f.x; ay += f.y;
        }
    }
    float dn = rsqrtf((float)(m + 1));
    float2 self = __half22float2(*(const __half2*)&tab[n * 16 + 2 * l]);
    int j0 = fbase + 2 * l, j1 = j0 + 1;
    float v0 = (j0 < H1) ? fmaxf(dn * (ax + self.x) + bb[2 * l], 0.f) : 0.f;
    float v1 = (j1 < H1) ? fmaxf(dn * (ay + self.y) + bb[2 * l + 1], 0.f) : 0.f;
    *(__half2*)&a_buf[n * 32 + fbase + 2 * l] =
        __halves2half2(__float2half(v0), __float2half(v1));
}

// 7) t2 halves = fp16( dinv * (a @ W2) ): same 16-lane-group micro-GEMM.
__global__ __launch_bounds__(256) void k_gemm2(const __half* __restrict__ a_buf,
                                               const float* __restrict__ W2,
                                               const int* __restrict__ rowptr,
                                               __half* __restrict__ t2lo,
                                               __half* __restrict__ t2hi) {
    __shared__ float Wp[H1 * 32];        // 3840 B, padded rows of 32
    __shared__ float as2[16 * 33];       // 2112 B, stride-33 pad
    __shared__ float dns[16];
    int t = threadIdx.x;
    for (int i = t; i < H1 * 32; i += 256) {
        int k = i >> 5, j = i & 31;
        Wp[i] = (j < H2) ? W2[k * H2 + j] : 0.f;
    }
    int nbase = blockIdx.x * 16;         // NN = 6250*16 exactly
    {
        // 16 rows x 32 halves = 256 half2: thread i loads half2 #i (coalesced)
        __half2 hv = *(const __half2*)&a_buf[nbase * 32 + 2 * t];
        float2 f = __half22float2(hv);
        int r = t >> 4;                  // row
        int c = (t & 15) * 2;            // col pair
        as2[r * 33 + c]     = f.x;
        as2[r * 33 + c + 1] = f.y;
    }
    if (t < 16) {
        int n = nbase + t;
        dns[t] = rsqrtf((float)(rowptr[n + 1] - rowptr[n] + 1));
    }
    __syncthreads();
    int g = t >> 4;
    int l = t & 15;
    float a0 = 0.f, a1 = 0.f;
#pragma unroll
    for (int k = 0; k < H1; ++k) {
        float ak = as2[g * 33 + k];                       // broadcast
        float2 w = *(const float2*)&Wp[k * 32 + 2 * l];
        a0 = fmaf(ak, w.x, a0);
        a1 = fmaf(ak, w.y, a1);
    }
    float dn = dns[g];
    __half2 hh = __halves2half2(__float2half(dn * a0), __float2half(dn * a1));
    int n = nbase + g;
    if (l < 8) *(__half2*)&t2lo[n * 16 + 2 * l] = hh;
    else       *(__half2*)&t2hi[n * 16 + 2 * (l - 8)] = hh;
}

// 8) layer-2 aggregate over ONE feature half -> out (+ self + b2)
__global__ __launch_bounds__(256) void k_aggh2(const int* __restrict__ ebuf,
                                               const int* __restrict__ rowptr,
                                               const __half* __restrict__ tab,
                                               const float* __restrict__ b2,
                                               int fbase,
                                               float* __restrict__ out) {
    __shared__ float bb[16];
    if (threadIdx.x < 16) {
        int j = fbase + threadIdx.x;
        bb[threadIdx.x] = (j < H2) ? b2[j] : 0.f;
    }
    __syncthreads();
    int g = threadIdx.x >> 3;
    int l = threadIdx.x & 7;
    int n = blockIdx.x * 32 + g;
    int beg = rowptr[n], end = rowptr[n + 1];
    int m = end - beg;
    int nfull = m & ~7;
    float ax = 0.f, ay = 0.f;
    for (int base = beg; base < beg + nfull; base += 8) {
        int sv = ebuf[base + l];
        int ss[8]; __half2 vv[8];
#pragma unroll
        for (int u = 0; u < 8; ++u) ss[u] = __shfl(sv, u, 8);
#pragma unroll
        for (int u = 0; u < 8; ++u) vv[u] = *(const __half2*)&tab[ss[u] * 16 + 2 * l];
#pragma unroll
        for (int u = 0; u < 8; ++u) { float2 f = __half22float2(vv[u]); ax += f.x; ay += f.y; }
    }
    int rem = m - nfull;
    if (rem) {
        int sv = (l < rem) ? ebuf[beg + nfull + l] : 0;
        for (int i = 0; i < rem; ++i) {
            int s = __shfl(sv, i, 8);
            float2 f = __half22float2(*(const __half2*)&tab[s * 16 + 2 * l]);
            ax += f.x; ay += f.y;
        }
    }
    float dn = rsqrtf((float)(m + 1));
    float2 self = __half22float2(*(const __half2*)&tab[n * 16 + 2 * l]);
    int j0 = fbase + 2 * l, j1 = j0 + 1;
    if (j0 < H2) out[n * H2 + j0] = dn * (ax + self.x) + bb[2 * l];
    if (j1 < H2) out[n * H2 + j1] = dn * (ay + self.y) + bb[2 * l + 1];
}

// ---------------------------------------------------------------------------
extern "C" void kernel_launch(void* const* d_in, const int* in_sizes, int n_in,
                              void* d_out, int out_size, void* d_ws, size_t ws_size,
                              hipStream_t stream) {
    const float* x   = (const float*)d_in[0];
    const int*   ei  = (const int*)d_in[1];   // [2, NE]: row 0 = src, row 1 = dst
    const float* W1  = (const float*)d_in[2];
    const float* b1  = (const float*)d_in[3];
    const float* W2  = (const float*)d_in[4];
    const float* b2  = (const float*)d_in[5];
    float*       out = (float*)d_out;

    const int* src = ei;
    const int* dst = ei + NE;

    // workspace layout (bytes, 128B-aligned) -- total 46,001,920
    char* ws = (char*)d_ws;
    int*    rowptr = (int*)   (ws + 0);           //   400,004 B (NN+1)
    int*    offT   = (int*)   (ws + 400128);      //   800,768 B (NB*NBLK)
    int*    bsum   = (int*)   (ws + 1201024);     //       784 B (SBLK)
    __half* h1lo   = (__half*)(ws + 1201920);     //  3,200,000 B (NN x 16)
    __half* h1hi   = (__half*)(ws + 4401920);     //  3,200,000 B
    __half* abuf   = (__half*)(ws + 7601920);     //  6,400,000 B (NN x 32)
    __half* t2lo   = (__half*)(ws + 14001920);    //  3,200,000 B
    __half* t2hi   = (__half*)(ws + 17201920);    //  3,200,000 B
    int*    ebuf   = (int*)   (ws + 20401920);    // 25,600,000 B

    k_hist <<<NBLK, 1024, 0, stream>>>(dst, offT);
    k_scan1<<<SBLK, 1024, 0, stream>>>(offT, bsum);
    k_scan2<<<1, 256, 0, stream>>>(bsum);
    k_scan3<<<SBLK, 1024, 0, stream>>>(offT, bsum);
    k_place<<<NBLK, 1024, 0, stream>>>(src, dst, offT, ebuf);
    k_bsort<<<NB, 1024, 0, stream>>>(ebuf, offT, rowptr);
    k_gemm1<<<NN / 16, 256, 0, stream>>>(x, W1, rowptr, h1lo, h1hi);
    k_aggh1<<<NN / 32, 256, 0, stream>>>(ebuf, rowptr, h1lo, b1, 0,  abuf);
    k_aggh1<<<NN / 32, 256, 0, stream>>>(ebuf, rowptr, h1hi, b1, 16, abuf);
    k_gemm2<<<NN / 16, 256, 0, stream>>>(abuf, W2, rowptr, t2lo, t2hi);
    k_aggh2<<<NN / 32, 256, 0, stream>>>(ebuf, rowptr, t2lo, b2, 0,  out);
    k_aggh2<<<NN / 32, 256, 0, stream>>>(ebuf, rowptr, t2hi, b2, 16, out);
}

// Round 15
// 287.243 us; speedup vs baseline: 1.2031x; 1.0307x over previous
//
#include <hip/hip_runtime.h>
#include <hip/hip_bf16.h>
#include <hip/hip_fp16.h>

// Problem constants (fixed by the reference)
#define NN 100000
#define NE 6400000
#define F_IN 50
#define H1 30
#define H2 25

// Bucketing constants
#define BSZ 128                    // dst nodes per bucket (dstoff = 7 bits)
#define NB 782                     // ceil(NN / BSZ)
#define NBLK 256                   // blocks for place
#define CHUNK 25000                // NE / NBLK (exact)
#define EPT ((CHUNK + 1023) / 1024)    // 25 edges per thread in k_place2
#define EPTB 12                    // keys per thread in k_bsort (1024 thr)
#define CAP (EPTB * 1024)          // 12,288 LDS-free reg capacity in k_bsort
#define CAPB 9216                  // fixed slots per bucket (mean 8184, sigma 90 -> 11+ sigma)

// ---------------------------------------------------------------------------
// 0) init global bucket cursors: gcur[b] = b*CAPB
__global__ __launch_bounds__(1024) void k_init(int* __restrict__ gcur) {
    int i = threadIdx.x;
    if (i < NB) gcur[i] = i * CAPB;
}

// 1) fused hist+scan+place: per-chunk LDS counting sort, global-cursor
//    reservation (one atomicAdd per (block,bucket)), coalesced run write-out
__global__ __launch_bounds__(1024) void k_place2(const int* __restrict__ src,
                                                 const int* __restrict__ dst,
                                                 int* __restrict__ gcur,
                                                 int* __restrict__ ebuf) {
    __shared__ int keys[CHUNK];      // 100,000 B
    __shared__ int cnt[NB];          // hist -> cursor -> end
    __shared__ int lstart[NB];       // local run starts
    __shared__ int gbase[NB];        // reserved global run starts
    __shared__ int scanT[1024];
    int t = threadIdx.x;
    int base = blockIdx.x * CHUNK;
    for (int i = t; i < NB; i += 1024) cnt[i] = 0;
    __syncthreads();
    // phase 1: load edges into registers (static indexing), LDS histogram
    int sreg[EPT], breg[EPT];
#pragma unroll
    for (int k = 0; k < EPT; ++k) {
        int idx = k * 1024 + t;
        if (idx < CHUNK) {
            int d = dst[base + idx];
            int s = src[base + idx];
            breg[k] = d >> 7;
            sreg[k] = (s << 7) | (d & 127);
            atomicAdd(&cnt[breg[k]], 1);
        }
    }
    __syncthreads();
    // phase 2: exclusive scan of cnt (NB=782 <= 1024) + global reservation
    int v = (t < NB) ? cnt[t] : 0;
    scanT[t] = v;
    __syncthreads();
    for (int off = 1; off < 1024; off <<= 1) {
        int u = (t >= off) ? scanT[t - off] : 0;
        __syncthreads();
        scanT[t] += u;
        __syncthreads();
    }
    if (t < NB) {
        int e = scanT[t] - v;
        lstart[t] = e;
        cnt[t] = e;
        gbase[t] = atomicAdd(&gcur[t], v);   // reserve v slots in bucket t
    }
    __syncthreads();
    // phase 3: scatter keys into LDS, bucket-grouped
#pragma unroll
    for (int k = 0; k < EPT; ++k) {
        int idx = k * 1024 + t;
        if (idx < CHUNK) {
            int p = atomicAdd(&cnt[breg[k]], 1);
            keys[p] = sreg[k];
        }
    }
    __syncthreads();
    // phase 4: per-bucket coalesced write-out (cnt[b] is now run end)
    int wv = t >> 6, ln = t & 63;
    for (int b = wv; b < NB; b += 16) {
        int s0 = lstart[b], e0 = cnt[b], gb = gbase[b];
        int lim = (b + 1) * CAPB;            // overflow guard (11-sigma, never hits)
        int cnt_run = e0 - s0;
        if (gb + cnt_run > lim) cnt_run = lim - gb;
        for (int off = ln; off < cnt_run; off += 64)
            ebuf[gb + off] = keys[s0 + off];
    }
}

// 2) within-bucket counting sort: keys staged in REGISTERS, 1024 threads,
//    ~1KB LDS -> full occupancy. Emits per-node [rowptr, rowend).
__global__ __launch_bounds__(1024) void k_bsort(int* __restrict__ ebuf,
                                                const int* __restrict__ gcur,
                                                int* __restrict__ rowptr,
                                                int* __restrict__ rowend) {
    __shared__ int cnt[BSZ];
    __shared__ int loc[BSZ];
    int b = blockIdx.x;
    int beg = b * CAPB;
    int end = gcur[b];
    int m = end - beg; if (m > CAP) m = CAP;
    int t = threadIdx.x;
    if (t < BSZ) cnt[t] = 0;
    __syncthreads();
    int keys[EPTB];
#pragma unroll
    for (int k = 0; k < EPTB; ++k) {
        int idx = k * 1024 + t;
        if (idx < m) {
            int key = ebuf[beg + idx];     // coalesced
            keys[k] = key;
            atomicAdd(&cnt[key & 127], 1);
        }
    }
    __syncthreads();
    // inclusive scan of cnt (first 128 threads)
    if (t < BSZ) loc[t] = cnt[t];
    __syncthreads();
    for (int off = 1; off < BSZ; off <<= 1) {
        int v = (t < BSZ && t >= off) ? loc[t - off] : 0;
        __syncthreads();
        if (t < BSZ) loc[t] += v;
        __syncthreads();
    }
    int nbase = b * BSZ;
    int nloc = NN - nbase; if (nloc > BSZ) nloc = BSZ;
    if (t < nloc) {
        rowptr[nbase + t] = beg + loc[t] - cnt[t];
        rowend[nbase + t] = beg + loc[t];
    }
    __syncthreads();
    if (t < BSZ) cnt[t] = beg + loc[t] - cnt[t];   // cursors
    __syncthreads();
#pragma unroll
    for (int k = 0; k < EPTB; ++k) {
        int idx = k * 1024 + t;
        if (idx < m) {
            int key = keys[k];
            int p = atomicAdd(&cnt[key & 127], 1);
            ebuf[p] = key >> 7;            // scattered within 36KB run -> L2 merges
        }
    }
}

// 3) h1 halves = fp16( dinv * (x @ W1) ): two [NN][16] tables.
//    16-lane-group-per-node micro-GEMM: low VGPR, small LDS, full occupancy.
__global__ __launch_bounds__(256) void k_gemm1(const float* __restrict__ x,
                                               const float* __restrict__ W1,
                                               const int* __restrict__ rowptr,
                                               const int* __restrict__ rowend,
                                               __half* __restrict__ h1lo,
                                               __half* __restrict__ h1hi) {
    __shared__ float Wp[F_IN * 32];      // 6400 B, padded rows of 32
    __shared__ float xs[16 * F_IN];      // 3200 B, 16 node rows
    __shared__ float dns[16];
    int t = threadIdx.x;
    for (int i = t; i < F_IN * 32; i += 256) {
        int k = i >> 5, j = i & 31;
        Wp[i] = (j < H1) ? W1[k * H1 + j] : 0.f;
    }
    int nbase = blockIdx.x * 16;         // NN = 6250*16 exactly
    for (int i = t; i < 16 * F_IN; i += 256)
        xs[i] = x[nbase * F_IN + i];     // coalesced
    if (t < 16) {
        int n = nbase + t;
        dns[t] = rsqrtf((float)(rowend[n] - rowptr[n] + 1));
    }
    __syncthreads();
    int g = t >> 4;                      // node group 0..15
    int l = t & 15;                      // lane: features 2l, 2l+1
    float a0 = 0.f, a1 = 0.f;
#pragma unroll
    for (int k = 0; k < F_IN; ++k) {
        float xk = xs[g * F_IN + k];                      // broadcast
        float2 w = *(const float2*)&Wp[k * 32 + 2 * l];   // conflict-free
        a0 = fmaf(xk, w.x, a0);
        a1 = fmaf(xk, w.y, a1);
    }
    float dn = dns[g];
    __half2 hh = __halves2half2(__float2half(dn * a0), __float2half(dn * a1));
    int n = nbase + g;
    if (l < 8) *(__half2*)&h1lo[n * 16 + 2 * l] = hh;
    else       *(__half2*)&h1hi[n * 16 + 2 * (l - 8)] = hh;
}

// 4) layer-1 aggregate over ONE feature half (table L2-resident): 8-lane
//    groups, half2/lane, 8-deep batch -> 64 rows in flight per wave.
//    Epilogue: bias+ReLU (per-feature) -> a_buf fp16 [NN][32]
__global__ __launch_bounds__(256) void k_aggh1(const int* __restrict__ ebuf,
                                               const int* __restrict__ rowptr,
                                               const int* __restrict__ rowend,
                                               const __half* __restrict__ tab,
                                               const float* __restrict__ b1,
                                               int fbase,
                                               __half* __restrict__ a_buf) {
    __shared__ float bb[16];
    if (threadIdx.x < 16) {
        int j = fbase + threadIdx.x;
        bb[threadIdx.x] = (j < H1) ? b1[j] : 0.f;
    }
    __syncthreads();
    int g = threadIdx.x >> 3;        // 0..31 node-group
    int l = threadIdx.x & 7;         // lane; features fbase+2l, fbase+2l+1
    int n = blockIdx.x * 32 + g;     // NN = 3125*32 exactly
    int beg = rowptr[n], end = rowend[n];
    int m = end - beg;
    int nfull = m & ~7;
    float ax = 0.f, ay = 0.f;
    for (int base = beg; base < beg + nfull; base += 8) {
        int sv = ebuf[base + l];
        int ss[8]; __half2 vv[8];
#pragma unroll
        for (int u = 0; u < 8; ++u) ss[u] = __shfl(sv, u, 8);
#pragma unroll
        for (int u = 0; u < 8; ++u) vv[u] = *(const __half2*)&tab[ss[u] * 16 + 2 * l];
#pragma unroll
        for (int u = 0; u < 8; ++u) { float2 f = __half22float2(vv[u]); ax += f.x; ay += f.y; }
    }
    int rem = m - nfull;
    if (rem) {
        int sv = (l < rem) ? ebuf[beg + nfull + l] : 0;
        for (int i = 0; i < rem; ++i) {   // group-uniform bound
            int s = __shfl(sv, i, 8);
            float2 f = __half22float2(*(const __half2*)&tab[s * 16 + 2 * l]);
            ax += f.x; ay += f.y;
        }
    }
    float dn = rsqrtf((float)(m + 1));
    float2 self = __half22float2(*(const __half2*)&tab[n * 16 + 2 * l]);
    int j0 = fbase + 2 * l, j1 = j0 + 1;
    float v0 = (j0 < H1) ? fmaxf(dn * (ax + self.x) + bb[2 * l], 0.f) : 0.f;
    float v1 = (j1 < H1) ? fmaxf(dn * (ay + self.y) + bb[2 * l + 1], 0.f) : 0.f;
    *(__half2*)&a_buf[n * 32 + fbase + 2 * l] =
        __halves2half2(__float2half(v0), __float2half(v1));
}

// 5) t2 halves = fp16( dinv * (a @ W2) ): same 16-lane-group micro-GEMM.
__global__ __launch_bounds__(256) void k_gemm2(const __half* __restrict__ a_buf,
                                               const float* __restrict__ W2,
                                               const int* __restrict__ rowptr,
                                               const int* __restrict__ rowend,
                                               __half* __restrict__ t2lo,
                                               __half* __restrict__ t2hi) {
    __shared__ float Wp[H1 * 32];        // 3840 B, padded rows of 32
    __shared__ float as2[16 * 33];       // 2112 B, stride-33 pad
    __shared__ float dns[16];
    int t = threadIdx.x;
    for (int i = t; i < H1 * 32; i += 256) {
        int k = i >> 5, j = i & 31;
        Wp[i] = (j < H2) ? W2[k * H2 + j] : 0.f;
    }
    int nbase = blockIdx.x * 16;         // NN = 6250*16 exactly
    {
        // 16 rows x 32 halves = 256 half2: thread i loads half2 #i (coalesced)
        __half2 hv = *(const __half2*)&a_buf[nbase * 32 + 2 * t];
        float2 f = __half22float2(hv);
        int r = t >> 4;                  // row
        int c = (t & 15) * 2;            // col pair
        as2[r * 33 + c]     = f.x;
        as2[r * 33 + c + 1] = f.y;
    }
    if (t < 16) {
        int n = nbase + t;
        dns[t] = rsqrtf((float)(rowend[n] - rowptr[n] + 1));
    }
    __syncthreads();
    int g = t >> 4;
    int l = t & 15;
    float a0 = 0.f, a1 = 0.f;
#pragma unroll
    for (int k = 0; k < H1; ++k) {
        float ak = as2[g * 33 + k];                       // broadcast
        float2 w = *(const float2*)&Wp[k * 32 + 2 * l];
        a0 = fmaf(ak, w.x, a0);
        a1 = fmaf(ak, w.y, a1);
    }
    float dn = dns[g];
    __half2 hh = __halves2half2(__float2half(dn * a0), __float2half(dn * a1));
    int n = nbase + g;
    if (l < 8) *(__half2*)&t2lo[n * 16 + 2 * l] = hh;
    else       *(__half2*)&t2hi[n * 16 + 2 * (l - 8)] = hh;
}

// 6) layer-2 aggregate over ONE feature half -> out (+ self + b2)
__global__ __launch_bounds__(256) void k_aggh2(const int* __restrict__ ebuf,
                                               const int* __restrict__ rowptr,
                                               const int* __restrict__ rowend,
                                               const __half* __restrict__ tab,
                                               const float* __restrict__ b2,
                                               int fbase,
                                               float* __restrict__ out) {
    __shared__ float bb[16];
    if (threadIdx.x < 16) {
        int j = fbase + threadIdx.x;
        bb[threadIdx.x] = (j < H2) ? b2[j] : 0.f;
    }
    __syncthreads();
    int g = threadIdx.x >> 3;
    int l = threadIdx.x & 7;
    int n = blockIdx.x * 32 + g;
    int beg = rowptr[n], end = rowend[n];
    int m = end - beg;
    int nfull = m & ~7;
    float ax = 0.f, ay = 0.f;
    for (int base = beg; base < beg + nfull; base += 8) {
        int sv = ebuf[base + l];
        int ss[8]; __half2 vv[8];
#pragma unroll
        for (int u = 0; u < 8; ++u) ss[u] = __shfl(sv, u, 8);
#pragma unroll
        for (int u = 0; u < 8; ++u) vv[u] = *(const __half2*)&tab[ss[u] * 16 + 2 * l];
#pragma unroll
        for (int u = 0; u < 8; ++u) { float2 f = __half22float2(vv[u]); ax += f.x; ay += f.y; }
    }
    int rem = m - nfull;
    if (rem) {
        int sv = (l < rem) ? ebuf[beg + nfull + l] : 0;
        for (int i = 0; i < rem; ++i) {
            int s = __shfl(sv, i, 8);
            float2 f = __half22float2(*(const __half2*)&tab[s * 16 + 2 * l]);
            ax += f.x; ay += f.y;
        }
    }
    float dn = rsqrtf((float)(m + 1));
    float2 self = __half22float2(*(const __half2*)&tab[n * 16 + 2 * l]);
    int j0 = fbase + 2 * l, j1 = j0 + 1;
    if (j0 < H2) out[n * H2 + j0] = dn * (ax + self.x) + bb[2 * l];
    if (j1 < H2) out[n * H2 + j1] = dn * (ay + self.y) + bb[2 * l + 1];
}

// ---------------------------------------------------------------------------
extern "C" void kernel_launch(void* const* d_in, const int* in_sizes, int n_in,
                              void* d_out, int out_size, void* d_ws, size_t ws_size,
                              hipStream_t stream) {
    const float* x   = (const float*)d_in[0];
    const int*   ei  = (const int*)d_in[1];   // [2, NE]: row 0 = src, row 1 = dst
    const float* W1  = (const float*)d_in[2];
    const float* b1  = (const float*)d_in[3];
    const float* W2  = (const float*)d_in[4];
    const float* b2  = (const float*)d_in[5];
    float*       out = (float*)d_out;

    const int* src = ei;
    const int* dst = ei + NE;

    // workspace layout (bytes, 128B-aligned) -- total 48,831,104
    // (round 2 proved ws_size >= 49,200,768)
    char* ws = (char*)d_ws;
    int*    rowptr = (int*)   (ws + 0);           //   400,000 B (NN)
    int*    rowend = (int*)   (ws + 400128);      //   400,000 B (NN)
    int*    gcur   = (int*)   (ws + 800256);      //     3,128 B (NB)
    __half* h1lo   = (__half*)(ws + 803456);      //  3,200,000 B (NN x 16)
    __half* h1hi   = (__half*)(ws + 4003456);     //  3,200,000 B
    __half* abuf   = (__half*)(ws + 7203456);     //  6,400,000 B (NN x 32)
    __half* t2lo   = (__half*)(ws + 13603456);    //  3,200,000 B
    __half* t2hi   = (__half*)(ws + 16803456);    //  3,200,000 B
    int*    ebuf   = (int*)   (ws + 20003456);    // 28,827,648 B (NB x CAPB)

    k_init  <<<1, 1024, 0, stream>>>(gcur);
    k_place2<<<NBLK, 1024, 0, stream>>>(src, dst, gcur, ebuf);
    k_bsort <<<NB, 1024, 0, stream>>>(ebuf, gcur, rowptr, rowend);
    k_gemm1 <<<NN / 16, 256, 0, stream>>>(x, W1, rowptr, rowend, h1lo, h1hi);
    k_aggh1 <<<NN / 32, 256, 0, stream>>>(ebuf, rowptr, rowend, h1lo, b1, 0,  abuf);
    k_aggh1 <<<NN / 32, 256, 0, stream>>>(ebuf, rowptr, rowend, h1hi, b1, 16, abuf);
    k_gemm2 <<<NN / 16, 256, 0, stream>>>(abuf, W2, rowptr, rowend, t2lo, t2hi);
    k_aggh2 <<<NN / 32, 256, 0, stream>>>(ebuf, rowptr, rowend, t2lo, b2, 0,  out);
    k_aggh2 <<<NN / 32, 256, 0, stream>>>(ebuf, rowptr, rowend, t2hi, b2, 16, out);
}

// Round 16
// 252.521 us; speedup vs baseline: 1.3685x; 1.1375x over previous
//
#include <hip/hip_runtime.h>
#include <hip/hip_bf16.h>
#include <hip/hip_fp16.h>

// Problem constants (fixed by the reference)
#define NN 100000
#define NE 6400000
#define F_IN 50
#define H1 30
#define H2 25

// Bucketing constants
#define BSZ 128                    // dst nodes per bucket (dstoff = 7 bits)
#define NB 782                     // ceil(NN / BSZ)
#define NBLK 256                   // blocks for place
#define CHUNK 25000                // NE / NBLK (exact)
#define EPT ((CHUNK + 1023) / 1024)    // 25 edges per thread in k_place2
#define EPTB 12                    // keys per thread in k_bsort (1024 thr)
#define CAP (EPTB * 1024)          // 12,288 reg capacity in k_bsort
#define CAPB 9216                  // fixed slots per bucket (mean 8184, sigma 90 -> 11+ sigma)

// fp16 pair <-> float2 helpers
__device__ __forceinline__ float2 h2f2(unsigned int u) {
    __half2 h;
    *reinterpret_cast<unsigned int*>(&h) = u;
    return __half22float2(h);
}
__device__ __forceinline__ unsigned int f2h2(float a, float b) {
    __half2 h = __halves2half2(__float2half(a), __float2half(b));
    return *reinterpret_cast<unsigned int*>(&h);
}

// ---------------------------------------------------------------------------
// 0) init global bucket cursors: gcur[b] = b*CAPB
__global__ __launch_bounds__(1024) void k_init(int* __restrict__ gcur) {
    int i = threadIdx.x;
    if (i < NB) gcur[i] = i * CAPB;
}

// 1) fused hist+scan+place: per-chunk LDS counting sort, global-cursor
//    reservation (one atomicAdd per (block,bucket)), coalesced run write-out
__global__ __launch_bounds__(1024) void k_place2(const int* __restrict__ src,
                                                 const int* __restrict__ dst,
                                                 int* __restrict__ gcur,
                                                 int* __restrict__ ebuf) {
    __shared__ int keys[CHUNK];      // 100,000 B
    __shared__ int cnt[NB];          // hist -> cursor -> end
    __shared__ int lstart[NB];       // local run starts
    __shared__ int gbase[NB];        // reserved global run starts
    __shared__ int scanT[1024];
    int t = threadIdx.x;
    int base = blockIdx.x * CHUNK;
    for (int i = t; i < NB; i += 1024) cnt[i] = 0;
    __syncthreads();
    // phase 1: load edges into registers (static indexing), LDS histogram
    int sreg[EPT], breg[EPT];
#pragma unroll
    for (int k = 0; k < EPT; ++k) {
        int idx = k * 1024 + t;
        if (idx < CHUNK) {
            int d = dst[base + idx];
            int s = src[base + idx];
            breg[k] = d >> 7;
            sreg[k] = (s << 7) | (d & 127);
            atomicAdd(&cnt[breg[k]], 1);
        }
    }
    __syncthreads();
    // phase 2: exclusive scan of cnt (NB=782 <= 1024) + global reservation
    int v = (t < NB) ? cnt[t] : 0;
    scanT[t] = v;
    __syncthreads();
    for (int off = 1; off < 1024; off <<= 1) {
        int u = (t >= off) ? scanT[t - off] : 0;
        __syncthreads();
        scanT[t] += u;
        __syncthreads();
    }
    if (t < NB) {
        int e = scanT[t] - v;
        lstart[t] = e;
        cnt[t] = e;
        gbase[t] = atomicAdd(&gcur[t], v);   // reserve v slots in bucket t
    }
    __syncthreads();
    // phase 3: scatter keys into LDS, bucket-grouped
#pragma unroll
    for (int k = 0; k < EPT; ++k) {
        int idx = k * 1024 + t;
        if (idx < CHUNK) {
            int p = atomicAdd(&cnt[breg[k]], 1);
            keys[p] = sreg[k];
        }
    }
    __syncthreads();
    // phase 4: per-bucket coalesced write-out (cnt[b] is now run end)
    int wv = t >> 6, ln = t & 63;
    for (int b = wv; b < NB; b += 16) {
        int s0 = lstart[b], e0 = cnt[b], gb = gbase[b];
        int lim = (b + 1) * CAPB;            // overflow guard (11-sigma, never hits)
        int cnt_run = e0 - s0;
        if (gb + cnt_run > lim) cnt_run = lim - gb;
        for (int off = ln; off < cnt_run; off += 64)
            ebuf[gb + off] = keys[s0 + off];
    }
}

// 2) within-bucket counting sort: keys staged in REGISTERS, 1024 threads,
//    ~1KB LDS -> full occupancy. Emits per-node [rowptr, rowend).
__global__ __launch_bounds__(1024) void k_bsort(int* __restrict__ ebuf,
                                                const int* __restrict__ gcur,
                                                int* __restrict__ rowptr,
                                                int* __restrict__ rowend) {
    __shared__ int cnt[BSZ];
    __shared__ int loc[BSZ];
    int b = blockIdx.x;
    int beg = b * CAPB;
    int end = gcur[b];
    int m = end - beg; if (m > CAP) m = CAP;
    int t = threadIdx.x;
    if (t < BSZ) cnt[t] = 0;
    __syncthreads();
    int keys[EPTB];
#pragma unroll
    for (int k = 0; k < EPTB; ++k) {
        int idx = k * 1024 + t;
        if (idx < m) {
            int key = ebuf[beg + idx];     // coalesced
            keys[k] = key;
            atomicAdd(&cnt[key & 127], 1);
        }
    }
    __syncthreads();
    // inclusive scan of cnt (first 128 threads)
    if (t < BSZ) loc[t] = cnt[t];
    __syncthreads();
    for (int off = 1; off < BSZ; off <<= 1) {
        int v = (t < BSZ && t >= off) ? loc[t - off] : 0;
        __syncthreads();
        if (t < BSZ) loc[t] += v;
        __syncthreads();
    }
    int nbase = b * BSZ;
    int nloc = NN - nbase; if (nloc > BSZ) nloc = BSZ;
    if (t < nloc) {
        rowptr[nbase + t] = beg + loc[t] - cnt[t];
        rowend[nbase + t] = beg + loc[t];
    }
    __syncthreads();
    if (t < BSZ) cnt[t] = beg + loc[t] - cnt[t];   // cursors
    __syncthreads();
#pragma unroll
    for (int k = 0; k < EPTB; ++k) {
        int idx = k * 1024 + t;
        if (idx < m) {
            int key = keys[k];
            int p = atomicAdd(&cnt[key & 127], 1);
            ebuf[p] = key >> 7;            // scattered within 36KB run -> L2 merges
        }
    }
}

// 3) h1p = fp16( dinv * (x @ W1) ), single [NN][32] table = one 64B line/row.
//    16-lane-group-per-node micro-GEMM: lane l -> features 2l, 2l+1.
__global__ __launch_bounds__(256) void k_gemm1(const float* __restrict__ x,
                                               const float* __restrict__ W1,
                                               const int* __restrict__ rowptr,
                                               const int* __restrict__ rowend,
                                               __half* __restrict__ h1p) {
    __shared__ float Wp[F_IN * 32];      // 6400 B, padded rows of 32 (pads 0)
    __shared__ float xs[16 * F_IN];      // 3200 B, 16 node rows
    __shared__ float dns[16];
    int t = threadIdx.x;
    for (int i = t; i < F_IN * 32; i += 256) {
        int k = i >> 5, j = i & 31;
        Wp[i] = (j < H1) ? W1[k * H1 + j] : 0.f;
    }
    int nbase = blockIdx.x * 16;         // NN = 6250*16 exactly
    for (int i = t; i < 16 * F_IN; i += 256)
        xs[i] = x[nbase * F_IN + i];     // coalesced
    if (t < 16) {
        int n = nbase + t;
        dns[t] = rsqrtf((float)(rowend[n] - rowptr[n] + 1));
    }
    __syncthreads();
    int g = t >> 4;                      // node group 0..15
    int l = t & 15;                      // lane: features 2l, 2l+1
    float a0 = 0.f, a1 = 0.f;
#pragma unroll
    for (int k = 0; k < F_IN; ++k) {
        float xk = xs[g * F_IN + k];                      // broadcast
        float2 w = *(const float2*)&Wp[k * 32 + 2 * l];   // conflict-free
        a0 = fmaf(xk, w.x, a0);
        a1 = fmaf(xk, w.y, a1);
    }
    float dn = dns[g];
    int n = nbase + g;
    *(__half2*)&h1p[n * 32 + 2 * l] =
        __halves2half2(__float2half(dn * a0), __float2half(dn * a1));
}

// 4) layer-1 aggregate, merged: 8-lane groups, uint2 (8B = 4 halves)/lane ->
//    ONE full 64B line per edge gather, 8-deep volley (proven structure).
//    Epilogue: bias+ReLU -> a_buf fp16 [NN][32] (pads 30,31 stay 0)
__global__ __launch_bounds__(256) void k_agg1(const int* __restrict__ ebuf,
                                              const int* __restrict__ rowptr,
                                              const int* __restrict__ rowend,
                                              const __half* __restrict__ tab,
                                              const float* __restrict__ b1,
                                              __half* __restrict__ a_buf) {
    __shared__ float bb[32];
    if (threadIdx.x < 32) bb[threadIdx.x] = (threadIdx.x < H1) ? b1[threadIdx.x] : 0.f;
    __syncthreads();
    int g = threadIdx.x >> 3;        // 0..31 node-group
    int l = threadIdx.x & 7;         // lane; features 4l..4l+3
    int n = blockIdx.x * 32 + g;     // NN = 3125*32 exactly
    int beg = rowptr[n], end = rowend[n];
    int m = end - beg;
    int nfull = m & ~7;
    float a0 = 0.f, a1 = 0.f, a2 = 0.f, a3 = 0.f;
    for (int base = beg; base < beg + nfull; base += 8) {
        int sv = ebuf[base + l];
        int ss[8]; uint2 vv[8];
#pragma unroll
        for (int u = 0; u < 8; ++u) ss[u] = __shfl(sv, u, 8);
#pragma unroll
        for (int u = 0; u < 8; ++u) vv[u] = *(const uint2*)&tab[ss[u] * 32 + 4 * l];
#pragma unroll
        for (int u = 0; u < 8; ++u) {
            float2 f0 = h2f2(vv[u].x), f1 = h2f2(vv[u].y);
            a0 += f0.x; a1 += f0.y; a2 += f1.x; a3 += f1.y;
        }
    }
    int rem = m - nfull;
    if (rem) {
        int sv = (l < rem) ? ebuf[beg + nfull + l] : 0;
        for (int i = 0; i < rem; ++i) {   // group-uniform bound
            int s = __shfl(sv, i, 8);
            uint2 v = *(const uint2*)&tab[s * 32 + 4 * l];
            float2 f0 = h2f2(v.x), f1 = h2f2(v.y);
            a0 += f0.x; a1 += f0.y; a2 += f1.x; a3 += f1.y;
        }
    }
    float dn = rsqrtf((float)(m + 1));
    uint2 sf = *(const uint2*)&tab[n * 32 + 4 * l];
    float2 s0 = h2f2(sf.x), s1 = h2f2(sf.y);
    int j = 4 * l;
    float v0 = fmaxf(dn * (a0 + s0.x) + bb[j],     0.f);
    float v1 = fmaxf(dn * (a1 + s0.y) + bb[j + 1], 0.f);
    float v2 = fmaxf(dn * (a2 + s1.x) + bb[j + 2], 0.f);
    float v3 = fmaxf(dn * (a3 + s1.y) + bb[j + 3], 0.f);
    uint2 o; o.x = f2h2(v0, v1); o.y = f2h2(v2, v3);
    *(uint2*)&a_buf[n * 32 + j] = o;     // pads (30,31) write 0: tab+bias are 0
}

// 5) t2p = fp16( dinv * (a @ W2) ), single [NN][32] table (pads 25..31 = 0).
__global__ __launch_bounds__(256) void k_gemm2(const __half* __restrict__ a_buf,
                                               const float* __restrict__ W2,
                                               const int* __restrict__ rowptr,
                                               const int* __restrict__ rowend,
                                               __half* __restrict__ t2p) {
    __shared__ float Wp[H1 * 32];        // 3840 B, padded rows of 32 (pads 0)
    __shared__ float as2[16 * 33];       // 2112 B, stride-33 pad
    __shared__ float dns[16];
    int t = threadIdx.x;
    for (int i = t; i < H1 * 32; i += 256) {
        int k = i >> 5, j = i & 31;
        Wp[i] = (j < H2) ? W2[k * H2 + j] : 0.f;
    }
    int nbase = blockIdx.x * 16;         // NN = 6250*16 exactly
    {
        // 16 rows x 32 halves = 256 half2: thread i loads half2 #i (coalesced)
        __half2 hv = *(const __half2*)&a_buf[nbase * 32 + 2 * t];
        float2 f = __half22float2(hv);
        int r = t >> 4;                  // row
        int c = (t & 15) * 2;            // col pair
        as2[r * 33 + c]     = f.x;
        as2[r * 33 + c + 1] = f.y;
    }
    if (t < 16) {
        int n = nbase + t;
        dns[t] = rsqrtf((float)(rowend[n] - rowptr[n] + 1));
    }
    __syncthreads();
    int g = t >> 4;
    int l = t & 15;
    float a0 = 0.f, a1 = 0.f;
#pragma unroll
    for (int k = 0; k < H1; ++k) {
        float ak = as2[g * 33 + k];                       // broadcast
        float2 w = *(const float2*)&Wp[k * 32 + 2 * l];
        a0 = fmaf(ak, w.x, a0);
        a1 = fmaf(ak, w.y, a1);
    }
    float dn = dns[g];
    int n = nbase + g;
    *(__half2*)&t2p[n * 32 + 2 * l] =
        __halves2half2(__float2half(dn * a0), __float2half(dn * a1));
}

// 6) layer-2 aggregate, merged -> out (+ self + b2); guarded fp32 stores
__global__ __launch_bounds__(256) void k_agg2(const int* __restrict__ ebuf,
                                              const int* __restrict__ rowptr,
                                              const int* __restrict__ rowend,
                                              const __half* __restrict__ tab,
                                              const float* __restrict__ b2,
                                              float* __restrict__ out) {
    __shared__ float bb[32];
    if (threadIdx.x < 32) bb[threadIdx.x] = (threadIdx.x < H2) ? b2[threadIdx.x] : 0.f;
    __syncthreads();
    int g = threadIdx.x >> 3;
    int l = threadIdx.x & 7;
    int n = blockIdx.x * 32 + g;
    int beg = rowptr[n], end = rowend[n];
    int m = end - beg;
    int nfull = m & ~7;
    float a0 = 0.f, a1 = 0.f, a2 = 0.f, a3 = 0.f;
    for (int base = beg; base < beg + nfull; base += 8) {
        int sv = ebuf[base + l];
        int ss[8]; uint2 vv[8];
#pragma unroll
        for (int u = 0; u < 8; ++u) ss[u] = __shfl(sv, u, 8);
#pragma unroll
        for (int u = 0; u < 8; ++u) vv[u] = *(const uint2*)&tab[ss[u] * 32 + 4 * l];
#pragma unroll
        for (int u = 0; u < 8; ++u) {
            float2 f0 = h2f2(vv[u].x), f1 = h2f2(vv[u].y);
            a0 += f0.x; a1 += f0.y; a2 += f1.x; a3 += f1.y;
        }
    }
    int rem = m - nfull;
    if (rem) {
        int sv = (l < rem) ? ebuf[beg + nfull + l] : 0;
        for (int i = 0; i < rem; ++i) {
            int s = __shfl(sv, i, 8);
            uint2 v = *(const uint2*)&tab[s * 32 + 4 * l];
            float2 f0 = h2f2(v.x), f1 = h2f2(v.y);
            a0 += f0.x; a1 += f0.y; a2 += f1.x; a3 += f1.y;
        }
    }
    float dn = rsqrtf((float)(m + 1));
    uint2 sf = *(const uint2*)&tab[n * 32 + 4 * l];
    float2 s0 = h2f2(sf.x), s1 = h2f2(sf.y);
    int j = 4 * l;
    if (j < H2)     out[n * H2 + j]     = dn * (a0 + s0.x) + bb[j];
    if (j + 1 < H2) out[n * H2 + j + 1] = dn * (a1 + s0.y) + bb[j + 1];
    if (j + 2 < H2) out[n * H2 + j + 2] = dn * (a2 + s1.x) + bb[j + 2];
    if (j + 3 < H2) out[n * H2 + j + 3] = dn * (a3 + s1.y) + bb[j + 3];
}

// ---------------------------------------------------------------------------
extern "C" void kernel_launch(void* const* d_in, const int* in_sizes, int n_in,
                              void* d_out, int out_size, void* d_ws, size_t ws_size,
                              hipStream_t stream) {
    const float* x   = (const float*)d_in[0];
    const int*   ei  = (const int*)d_in[1];   // [2, NE]: row 0 = src, row 1 = dst
    const float* W1  = (const float*)d_in[2];
    const float* b1  = (const float*)d_in[3];
    const float* W2  = (const float*)d_in[4];
    const float* b2  = (const float*)d_in[5];
    float*       out = (float*)d_out;

    const int* src = ei;
    const int* dst = ei + NE;

    // workspace layout (bytes, 128B-aligned) -- total 48,831,104
    char* ws = (char*)d_ws;
    int*    rowptr = (int*)   (ws + 0);           //   400,000 B (NN)
    int*    rowend = (int*)   (ws + 400128);      //   400,000 B (NN)
    int*    gcur   = (int*)   (ws + 800256);      //     3,128 B (NB)
    __half* h1p    = (__half*)(ws + 803456);      //  6,400,000 B (NN x 32)
    __half* abuf   = (__half*)(ws + 7203456);     //  6,400,000 B (NN x 32)
    __half* t2p    = (__half*)(ws + 13603456);    //  6,400,000 B (NN x 32)
    int*    ebuf   = (int*)   (ws + 20003456);    // 28,827,648 B (NB x CAPB)

    k_init  <<<1, 1024, 0, stream>>>(gcur);
    k_place2<<<NBLK, 1024, 0, stream>>>(src, dst, gcur, ebuf);
    k_bsort <<<NB, 1024, 0, stream>>>(ebuf, gcur, rowptr, rowend);
    k_gemm1 <<<NN / 16, 256, 0, stream>>>(x, W1, rowptr, rowend, h1p);
    k_agg1  <<<NN / 32, 256, 0, stream>>>(ebuf, rowptr, rowend, h1p, b1, abuf);
    k_gemm2 <<<NN / 16, 256, 0, stream>>>(abuf, W2, rowptr, rowend, t2p);
    k_agg2  <<<NN / 32, 256, 0, stream>>>(ebuf, rowptr, rowend, t2p, b2, out);
}